// Round 4
// baseline (264.664 us; speedup 1.0000x reference)
//
#include <hip/hip_runtime.h>
#include <math.h>

#define QN   16384
#define CCH  256
#define NCAM 6
#define HFD  32
#define WFD  88
#define DDD  64
#define BEVH 128
#define BEVW 128
#define IMGW 704.0f
#define IMGH 256.0f
#define EPSV 1e-5f

typedef __attribute__((ext_vector_type(8))) short bf8_t;    // 8 bf16 (MFMA operand)
typedef __attribute__((ext_vector_type(8))) unsigned short us8;
typedef __attribute__((ext_vector_type(4))) unsigned short us4;
typedef __attribute__((ext_vector_type(4))) float f4_t;

__device__ __forceinline__ float sigmoidf_(float x){ return 1.0f/(1.0f+__expf(-x)); }

__device__ __forceinline__ unsigned short f2bf(float f){
    unsigned int b = __float_as_uint(f);
    b += 0x7FFFu + ((b >> 16) & 1u);
    return (unsigned short)(b >> 16);
}
__device__ __forceinline__ float bf2f(unsigned short u){
    return __uint_as_float(((unsigned int)u) << 16);
}

// ================= k_prep: feat transpose + weight pack + ssum zero =================
// blocks [0,4224): feat (6,256,32,88) f32 -> feat_tH (6,2816,256) bf16
// blocks [4224,6528): conv_w (co,ci,3,3) -> wtH bf16 [kk][co][ci]
__global__ __launch_bounds__(256) void k_prep(const float* __restrict__ feat, unsigned short* __restrict__ feat_tH,
                                              const float* __restrict__ cw, unsigned short* __restrict__ wtH,
                                              float* __restrict__ ssum){
    int b = blockIdx.x;
    if (b < 4224){
        __shared__ float tile[32][33];
        int n   = b / 704;          // 88*8 = 704
        int rem = b - n*704;
        int cb  = (rem / 88) * 32;
        int pb  = (rem % 88) * 32;
        int tx = threadIdx.x & 31, ty = threadIdx.x >> 5;
        for (int r = ty; r < 32; r += 8)
            tile[r][tx] = feat[(size_t)(n*256 + cb + r)*2816 + pb + tx];
        __syncthreads();
        for (int r = ty; r < 32; r += 8)
            feat_tH[(size_t)(n*2816 + pb + r)*256 + cb + tx] = f2bf(tile[tx][r]);
    } else {
        int b2 = b - 4224;
        if (b2 == 0) ssum[threadIdx.x] = 0.f;
        int idx = b2*256 + threadIdx.x;     // < 9*256*256 exactly
        int ci = idx & 255;
        int co = (idx >> 8) & 255;
        int kk = idx >> 16;
        wtH[idx] = f2bf(cw[(size_t)(co*256 + ci)*9 + kk]);
    }
}

// ================= k_geomagg: fused geometry + feature aggregation =================
// 2048 blocks x 256 thr; each block handles 8 queries (wave handles 2)
__global__ __launch_bounds__(256) void k_geomagg(
    const float* __restrict__ bq, const float* __restrict__ bpos,
    const float* __restrict__ refp, const float* __restrict__ pcr,
    const float* __restrict__ l2i, const float* __restrict__ dpr,
    const float* __restrict__ w_pos, const float* __restrict__ b_pos,
    const float* __restrict__ w_img, const float* __restrict__ b_img,
    const float* __restrict__ w_att, const float* __restrict__ b_att,
    const unsigned short* __restrict__ feat_tH,
    unsigned short* __restrict__ aggH, float* __restrict__ out_rp)
{
    __shared__ int   so_l[192];
    __shared__ float sw_l[192];
    int q0 = blockIdx.x * 8;
    int tid = threadIdx.x;
    int wid = tid >> 6, lane = tid & 63;
    int c0 = lane * 4;

    #pragma unroll
    for (int qi = 0; qi < 2; qi++){
        int ql = wid*2 + qi;
        int q  = q0 + ql;

        const float4 a4 = *(const float4*)(bq  + (size_t)q*CCH + c0);
        const float4 b4 = *(const float4*)(bpos+ (size_t)q*CCH + c0);
        float qv[4] = {a4.x+b4.x, a4.y+b4.y, a4.z+b4.z, a4.w+b4.w};

        float s[19];
        {
            const float4 wp = *(const float4*)(w_pos + c0);
            s[0] = qv[0]*wp.x + qv[1]*wp.y + qv[2]*wp.z + qv[3]*wp.w;
        }
        #pragma unroll
        for (int j=0;j<6;j++){
            float a = 0.f;
            #pragma unroll
            for (int k=0;k<4;k++) a += qv[k]*w_att[(c0+k)*6 + j];
            s[1+j] = a;
        }
        #pragma unroll
        for (int j=0;j<12;j++){
            float a = 0.f;
            #pragma unroll
            for (int k=0;k<4;k++) a += qv[k]*w_img[(c0+k)*12 + j];
            s[7+j] = a;
        }
        #pragma unroll
        for (int off=1; off<64; off<<=1){
            #pragma unroll
            for (int i=0;i<19;i++) s[i] += __shfl_xor(s[i], off, 64);
        }

        float pos_off = s[0] + b_pos[0];
        float rx = refp[q*3+0], ry = refp[q*3+1], rz = refp[q*3+2];
        float zc_ = fminf(fmaxf(rz, 0.f), 1.f);
        float inv = logf(fmaxf(zc_, EPSV) / fmaxf(1.f - zc_, EPSV));
        float znew = sigmoidf_(inv + pos_off);

        if (lane == 0){
            out_rp[q*3+0] = rx; out_rp[q*3+1] = ry; out_rp[q*3+2] = znew;
        }
        if (lane < NCAM){
            int n = lane;
            float att  = s[1+n] + b_att[n];
            float offx = (s[7+2*n]   + b_img[2*n])   / (float)WFD;
            float offy = (s[7+2*n+1] + b_img[2*n+1]) / (float)HFD;
            float lo0=pcr[0], lo1=pcr[1], lo2=pcr[2];
            float hi0=pcr[3], hi1=pcr[4], hi2=pcr[5];
            float px = rx*(hi0-lo0)+lo0, py = ry*(hi1-lo1)+lo1, pz = znew*(hi2-lo2)+lo2;
            const float* M = l2i + n*16;
            float cx = M[0]*px + M[1]*py + M[2]*pz  + M[3];
            float cy = M[4]*px + M[5]*py + M[6]*pz  + M[7];
            float cz = M[8]*px + M[9]*py + M[10]*pz + M[11];
            bool m = cz > EPSV;
            float zdiv = fmaxf(cz, EPSV);
            float u = (cx/zdiv)/IMGW; u = (u - 0.5f)*2.f;
            float v = (cy/zdiv)/IMGH; v = (v - 0.5f)*2.f;
            m = m && (u > -1.f) && (u < 1.f) && (v > -1.f) && (v < 1.f);
            float rdn = (cz/(float)DDD - 0.5f)*2.f;
            m = m && (rdn > -1.f) && (rdn < 1.f);

            int base = ql*24 + n*4;
            float wq = 0.f, xs = 0.f, ys = 0.f;
            if (m){
                float u2 = u + offx, v2 = v + offy;
                xs = (u2 + 1.f)*0.5f*WFD - 0.5f;
                ys = (v2 + 1.f)*0.5f*HFD - 0.5f;
                float zs = (rdn + 1.f)*0.5f*DDD - 0.5f;
                float fx = floorf(xs), fy = floorf(ys), fz = floorf(zs);
                int x0=(int)fx, y0=(int)fy, z0=(int)fz;
                float wx = xs-fx, wy = ys-fy, wz = zs-fz;
                float dp = 0.f;
                const float* vol = dpr + (size_t)n*DDD*HFD*WFD;
                #pragma unroll
                for (int dz=0; dz<2; dz++)
                #pragma unroll
                for (int dy=0; dy<2; dy++)
                #pragma unroll
                for (int dx=0; dx<2; dx++){
                    int ix=x0+dx, iy=y0+dy, iz=z0+dz;
                    if (ix>=0 && ix<WFD && iy>=0 && iy<HFD && iz>=0 && iz<DDD){
                        float ww = (dx?wx:1.f-wx)*(dy?wy:1.f-wy)*(dz?wz:1.f-wz);
                        dp += ww * vol[(size_t)(iz*HFD+iy)*WFD + ix];
                    }
                }
                wq = sigmoidf_(att) * dp;
            }
            if (m && wq != 0.f){
                float fx = floorf(xs), fy = floorf(ys);
                int x0=(int)fx, y0=(int)fy;
                float wx = xs-fx, wy = ys-fy;
                float cwv[4] = {(1.f-wx)*(1.f-wy), wx*(1.f-wy), (1.f-wx)*wy, wx*wy};
                int xi[4] = {x0, x0+1, x0, x0+1};
                int yi[4] = {y0, y0, y0+1, y0+1};
                #pragma unroll
                for (int k=0;k<4;k++){
                    bool ok = (xi[k]>=0 && xi[k]<WFD && yi[k]>=0 && yi[k]<HFD);
                    so_l[base+k] = ok ? ((n*HFD + yi[k])*WFD + xi[k]) : 0;
                    sw_l[base+k] = ok ? wq*cwv[k] : 0.f;
                }
            } else {
                #pragma unroll
                for (int k=0;k<4;k++){ so_l[base+k] = 0; sw_l[base+k] = 0.f; }
            }
        }
    }
    __syncthreads();

    // gather phase: wave handles its 2 queries, lane covers 4 channels
    int c4 = lane * 4;
    #pragma unroll
    for (int qi=0; qi<2; qi++){
        int ql = wid*2 + qi;
        float a0=0.f, a1=0.f, a2=0.f, a3=0.f;
        #pragma unroll
        for (int k=0;k<24;k++){
            float w = sw_l[ql*24+k];
            if (w != 0.f){
                us4 v = *(const us4*)(feat_tH + (size_t)so_l[ql*24+k]*CCH + c4);
                a0 += w * bf2f(v.x);
                a1 += w * bf2f(v.y);
                a2 += w * bf2f(v.z);
                a3 += w * bf2f(v.w);
            }
        }
        us4 o; o.x = f2bf(a0); o.y = f2bf(a1); o.z = f2bf(a2); o.w = f2bf(a3);
        *(us4*)(aggH + (size_t)(q0+ql)*CCH + c4) = o;
    }
}

// ================= k_conv2: 3x3 conv + BN + ReLU + SE-sum, kw-folded MFMA =================
// block: 512 thr (8 waves), tile 128 px (full BEV row) x 64 co; stages = 3 kh x 4 ci-chunks
__global__ __launch_bounds__(512, 4) void k_conv2(const unsigned short* __restrict__ aggH,
    const unsigned short* __restrict__ wtH, const float* __restrict__ conv_b,
    const float* __restrict__ bn_g, const float* __restrict__ bn_b,
    const float* __restrict__ bn_m, const float* __restrict__ bn_v,
    float* __restrict__ xN, float* __restrict__ ssum)
{
    __shared__ unsigned short Al[130][72];       // rows: input px w = row-1, w in [-1..128]
    __shared__ unsigned short Bl[3][64][72];     // [kw][co][ci]
    __shared__ float sacc[64];

    int h   = blockIdx.x;           // BEV row
    int co0 = blockIdx.y * 64;
    int tid  = threadIdx.x;
    int lane = tid & 63, wid = tid >> 6;
    int m_wave = (wid & 3) * 32;
    int n_wave = (wid >> 2) * 32;
    int l15 = lane & 15, quad = lane >> 4;

    f4_t acc[2][2];
    #pragma unroll
    for (int i=0;i<2;i++)
    #pragma unroll
    for (int j=0;j<2;j++) acc[i][j] = (f4_t){0.f,0.f,0.f,0.f};

    // staging assignments
    int aw = tid >> 2;              // input px w 0..127 -> Al row aw+1
    int sa = (tid & 3) * 16;        // ci segment (shorts)
    int bco = tid >> 3;             // co 0..63
    int sb  = (tid & 7) * 8;        // ci segment (shorts)

    // init always-zero halo rows + sacc (covered by first barrier)
    if (tid < 8){
        int r = (tid >> 2) ? 129 : 0;
        int sg = (tid & 3) * 16;
        us8 z = (us8){0,0,0,0,0,0,0,0};
        *(us8*)&Al[r][sg]   = z;
        *(us8*)&Al[r][sg+8] = z;
    }
    if (tid < 64) sacc[tid] = 0.f;

    us8 ra0, ra1, rb0, rb1, rb2;
    const us8 z8 = (us8){0,0,0,0,0,0,0,0};

    // stage s: kh = s>>2, ci0 = (s&3)*64
    #define LOADSTAGE(s) { \
        int kh_ = (s) >> 2; int ci0_ = ((s) & 3) << 6; \
        int ph_ = h + kh_ - 1; \
        if (ph_ >= 0 && ph_ < BEVH){ \
            const unsigned short* ap_ = aggH + ((size_t)(ph_*BEVW + aw)*CCH + ci0_ + sa); \
            ra0 = *(const us8*)ap_; ra1 = *(const us8*)(ap_ + 8); \
        } else { ra0 = z8; ra1 = z8; } \
        const unsigned short* bp_ = wtH + ((size_t)(kh_*3*256) + co0 + bco)*CCH + ci0_ + sb; \
        rb0 = *(const us8*)bp_; \
        rb1 = *(const us8*)(bp_ + 256*CCH); \
        rb2 = *(const us8*)(bp_ + 512*CCH); \
    }

    LOADSTAGE(0);
    for (int s=0; s<12; s++){
        __syncthreads();
        *(us8*)&Al[aw+1][sa]   = ra0;
        *(us8*)&Al[aw+1][sa+8] = ra1;
        *(us8*)&Bl[0][bco][sb] = rb0;
        *(us8*)&Bl[1][bco][sb] = rb1;
        *(us8*)&Bl[2][bco][sb] = rb2;
        __syncthreads();
        if (s < 11) LOADSTAGE(s+1);
        #pragma unroll
        for (int kw=0; kw<3; kw++){
            #pragma unroll
            for (int ks=0; ks<2; ks++){
                bf8_t af0 = *(bf8_t*)&Al[m_wave      + l15 + kw][ks*32 + quad*8];
                bf8_t af1 = *(bf8_t*)&Al[m_wave + 16 + l15 + kw][ks*32 + quad*8];
                bf8_t bf0 = *(bf8_t*)&Bl[kw][n_wave      + l15][ks*32 + quad*8];
                bf8_t bf1 = *(bf8_t*)&Bl[kw][n_wave + 16 + l15][ks*32 + quad*8];
                acc[0][0] = __builtin_amdgcn_mfma_f32_16x16x32_bf16(af0, bf0, acc[0][0], 0, 0, 0);
                acc[0][1] = __builtin_amdgcn_mfma_f32_16x16x32_bf16(af0, bf1, acc[0][1], 0, 0, 0);
                acc[1][0] = __builtin_amdgcn_mfma_f32_16x16x32_bf16(af1, bf0, acc[1][0], 0, 0, 0);
                acc[1][1] = __builtin_amdgcn_mfma_f32_16x16x32_bf16(af1, bf1, acc[1][1], 0, 0, 0);
            }
        }
    }
    #undef LOADSTAGE

    // epilogue: bias + BN + ReLU, write xN, accumulate SE partial
    #pragma unroll
    for (int j=0;j<2;j++){
        int col = n_wave + j*16 + l15;
        int co = co0 + col;
        float sc = bn_g[co] * rsqrtf(bn_v[co] + 1e-5f);
        float sh = bn_b[co] - bn_m[co]*sc;
        float cb = conv_b[co];
        float part = 0.f;
        #pragma unroll
        for (int i=0;i<2;i++){
            #pragma unroll
            for (int r=0;r<4;r++){
                int m = m_wave + i*16 + quad*4 + r;
                int p = h*BEVW + m;
                float y = fmaxf((acc[i][j][r] + cb)*sc + sh, 0.f);
                xN[(size_t)p*CCH + co] = y;
                part += y;
            }
        }
        atomicAdd(&sacc[col], part);
    }
    __syncthreads();
    if (tid < 64) atomicAdd(&ssum[co0 + tid], sacc[tid]);
}

// ================= k_maps2: SE scale (recomputed per block) + CBAM channel maps =================
// 256 blocks x 256 thr; block handles 64 pixels
__global__ __launch_bounds__(256) void k_maps2(const float* __restrict__ xN,
    const float* __restrict__ ssum, const float* __restrict__ se_w, const float* __restrict__ se_b,
    float* __restrict__ scale_g, float* __restrict__ amax, float* __restrict__ amean)
{
    __shared__ float smv[256];
    __shared__ float scl[256];
    int t = threadIdx.x;
    smv[t] = ssum[t] * (1.f/16384.f);
    __syncthreads();
    float acc = se_b[t];
    for (int k=0; k<256; k+=4){
        float4 w4 = *(const float4*)&se_w[(size_t)t*256 + k];
        acc += smv[k]*w4.x + smv[k+1]*w4.y + smv[k+2]*w4.z + smv[k+3]*w4.w;
    }
    float sv = sigmoidf_(acc);
    scl[t] = sv;
    if (blockIdx.x == 0) scale_g[t] = sv;
    __syncthreads();

    int wid = t >> 6, lane = t & 63;
    int p0 = blockIdx.x * 64;
    float4 sc = *(const float4*)&scl[lane*4];
    for (int i=0; i<16; i++){
        int p = p0 + i*4 + wid;
        float4 v = *(const float4*)&xN[(size_t)p*CCH + lane*4];
        float a = v.x*sc.x, b = v.y*sc.y, c = v.z*sc.z, d = v.w*sc.w;
        float mx = fmaxf(fmaxf(a,b), fmaxf(c,d));
        float sm = a+b+c+d;
        #pragma unroll
        for (int off=1; off<64; off<<=1){
            mx = fmaxf(mx, __shfl_xor(mx, off, 64));
            sm += __shfl_xor(sm, off, 64);
        }
        if (lane == 0){ amax[p] = mx; amean[p] = sm*(1.f/256.f); }
    }
}

// ================= k_final2: CBAM 7x7 (in-block) + final scaling =================
// 256 blocks x 256 thr; block handles row h, half (b&1): 64 px
__global__ __launch_bounds__(256) void k_final2(const float* __restrict__ xN,
    const float* __restrict__ scale_g, const float* __restrict__ amax, const float* __restrict__ amean,
    const float* __restrict__ cw, const float* __restrict__ cb, float* __restrict__ out)
{
    __shared__ float am2[7][128];
    __shared__ float av2[7][128];
    __shared__ float wcb[98];
    __shared__ float scl[256];
    __shared__ float amap_l[64];

    int b = blockIdx.x;
    int h  = b >> 1;
    int w0 = (b & 1) * 64;
    int t = threadIdx.x;

    scl[t] = scale_g[t];
    if (t < 98) wcb[t] = cw[t];
    for (int idx = t; idx < 896; idx += 256){
        int r = idx >> 7, c = idx & 127;
        int ph = h + r - 3;
        bool ok = (ph >= 0 && ph < BEVH);
        am2[r][c] = ok ? amax[ph*BEVW + c] : 0.f;
        av2[r][c] = ok ? amean[ph*BEVW + c] : 0.f;
    }
    __syncthreads();

    if (t < 64){
        int px = w0 + t;
        float acc = cb[0];
        #pragma unroll
        for (int kh=0; kh<7; kh++){
            #pragma unroll
            for (int kw=0; kw<7; kw++){
                int pw = px + kw - 3;
                if (pw >= 0 && pw < BEVW)
                    acc += am2[kh][pw]*wcb[kh*7+kw] + av2[kh][pw]*wcb[49 + kh*7+kw];
            }
        }
        amap_l[t] = sigmoidf_(acc);
    }
    __syncthreads();

    int lane = t & 63, sub = t >> 6;
    int c4 = lane * 4;
    float4 sc = *(const float4*)&scl[c4];
    for (int i=0; i<16; i++){
        int pxl = sub*16 + i;
        int p = h*BEVW + w0 + pxl;
        float am = amap_l[pxl];
        float4 v = *(const float4*)&xN[(size_t)p*CCH + c4];
        float4 o;
        o.x = v.x*sc.x*am; o.y = v.y*sc.y*am; o.z = v.z*sc.z*am; o.w = v.w*sc.w*am;
        *(float4*)&out[(size_t)p*CCH + c4] = o;
    }
}

extern "C" void kernel_launch(void* const* d_in, const int* in_sizes, int n_in,
                              void* d_out, int out_size, void* d_ws, size_t ws_size,
                              hipStream_t stream) {
    const float* feat   = (const float*)d_in[0];
    const float* bq     = (const float*)d_in[1];
    const float* bpos   = (const float*)d_in[2];
    const float* refp   = (const float*)d_in[3];
    const float* pcr    = (const float*)d_in[4];
    const float* l2i    = (const float*)d_in[5];
    const float* dpr    = (const float*)d_in[6];
    const float* w_pos  = (const float*)d_in[7];
    const float* b_pos  = (const float*)d_in[8];
    const float* w_img  = (const float*)d_in[9];
    const float* b_img  = (const float*)d_in[10];
    const float* w_att  = (const float*)d_in[11];
    const float* b_att  = (const float*)d_in[12];
    const float* conv_w = (const float*)d_in[13];
    const float* conv_b = (const float*)d_in[14];
    const float* bn_g   = (const float*)d_in[15];
    const float* bn_b   = (const float*)d_in[16];
    const float* bn_m   = (const float*)d_in[17];
    const float* bn_v   = (const float*)d_in[18];
    const float* se_w   = (const float*)d_in[19];
    const float* se_b   = (const float*)d_in[20];
    const float* cbw    = (const float*)d_in[21];
    const float* cbb    = (const float*)d_in[22];
    float* out = (float*)d_out;

    float* ws = (float*)d_ws;
    size_t o = 0;
    unsigned short* feat_tH = (unsigned short*)(ws + o); o += (size_t)6*2816*128;  // bf16
    unsigned short* wtH  = (unsigned short*)(ws + o); o += (size_t)9*256*128;      // bf16
    unsigned short* aggH = (unsigned short*)(ws + o); o += (size_t)QN*128;         // bf16
    float* xN      = ws + o;  o += (size_t)QN*256;
    float* ssum    = ws + o;  o += 256;
    float* scale_g = ws + o;  o += 256;
    float* amax    = ws + o;  o += QN;
    float* amean   = ws + o;  o += QN;

    k_prep<<<6528, 256, 0, stream>>>(feat, feat_tH, conv_w, wtH, ssum);
    k_geomagg<<<2048, 256, 0, stream>>>(bq, bpos, refp, pcr, l2i, dpr,
                                        w_pos, b_pos, w_img, b_img, w_att, b_att,
                                        feat_tH, aggH, out + (size_t)QN*256);
    k_conv2<<<dim3(128,4), 512, 0, stream>>>(aggH, wtH, conv_b, bn_g, bn_b, bn_m, bn_v, xN, ssum);
    k_maps2<<<256, 256, 0, stream>>>(xN, ssum, se_w, se_b, scale_g, amax, amean);
    k_final2<<<256, 256, 0, stream>>>(xN, scale_g, amax, amean, cbw, cbb, out);
}

// Round 5
// 246.078 us; speedup vs baseline: 1.0755x; 1.0755x over previous
//
#include <hip/hip_runtime.h>
#include <math.h>

#define QN   16384
#define CCH  256
#define NCAM 6
#define HFD  32
#define WFD  88
#define DDD  64
#define BEVH 128
#define BEVW 128
#define IMGW 704.0f
#define IMGH 256.0f
#define EPSV 1e-5f

typedef __attribute__((ext_vector_type(8))) short bf8_t;    // 8 bf16 (MFMA operand)
typedef __attribute__((ext_vector_type(8))) unsigned short us8;
typedef __attribute__((ext_vector_type(4))) unsigned short us4;
typedef __attribute__((ext_vector_type(4))) float f4_t;

__device__ __forceinline__ float sigmoidf_(float x){ return 1.0f/(1.0f+__expf(-x)); }

__device__ __forceinline__ unsigned short f2bf(float f){
    unsigned int b = __float_as_uint(f);
    b += 0x7FFFu + ((b >> 16) & 1u);
    return (unsigned short)(b >> 16);
}
__device__ __forceinline__ float bf2f(unsigned short u){
    return __uint_as_float(((unsigned int)u) << 16);
}

// ================= k_prep: feat transpose + weight pack + ssum zero =================
__global__ __launch_bounds__(256) void k_prep(const float* __restrict__ feat, unsigned short* __restrict__ feat_tH,
                                              const float* __restrict__ cw, unsigned short* __restrict__ wtH,
                                              float* __restrict__ ssum){
    int b = blockIdx.x;
    if (b < 4224){
        __shared__ float tile[32][33];
        int n   = b / 704;          // 88*8 = 704
        int rem = b - n*704;
        int cb  = (rem / 88) * 32;
        int pb  = (rem % 88) * 32;
        int tx = threadIdx.x & 31, ty = threadIdx.x >> 5;
        for (int r = ty; r < 32; r += 8)
            tile[r][tx] = feat[(size_t)(n*256 + cb + r)*2816 + pb + tx];
        __syncthreads();
        for (int r = ty; r < 32; r += 8)
            feat_tH[(size_t)(n*2816 + pb + r)*256 + cb + tx] = f2bf(tile[tx][r]);
    } else {
        int b2 = b - 4224;
        if (b2 == 0) ssum[threadIdx.x] = 0.f;
        int idx = b2*256 + threadIdx.x;     // < 9*256*256 exactly
        int ci = idx & 255;
        int co = (idx >> 8) & 255;
        int kk = idx >> 16;
        wtH[idx] = f2bf(cw[(size_t)(co*256 + ci)*9 + kk]);
    }
}

// ================= k_geomagg: fused geometry + feature aggregation =================
// 2048 blocks x 256 thr; each block handles 8 queries (wave handles 2)
// v5: projection weights staged in LDS as wl[j][c] (f32) -> ds_read_b128 instead of
//     per-lane strided global loads (which touched 64 cache lines per instruction)
__global__ __launch_bounds__(256) void k_geomagg(
    const float* __restrict__ bq, const float* __restrict__ bpos,
    const float* __restrict__ refp, const float* __restrict__ pcr,
    const float* __restrict__ l2i, const float* __restrict__ dpr,
    const float* __restrict__ w_pos, const float* __restrict__ b_pos,
    const float* __restrict__ w_img, const float* __restrict__ b_img,
    const float* __restrict__ w_att, const float* __restrict__ b_att,
    const unsigned short* __restrict__ feat_tH,
    unsigned short* __restrict__ aggH, float* __restrict__ out_rp)
{
    __shared__ float wl[19][256];   // [j][c]: 0=pos, 1..6=att, 7..18=img
    __shared__ int   so_l[192];
    __shared__ float sw_l[192];
    int q0 = blockIdx.x * 8;
    int tid = threadIdx.x;
    int wid = tid >> 6, lane = tid & 63;
    int c0 = lane * 4;

    // ---- stage projection weights (coalesced reads, L2-hot) ----
    wl[0][tid] = w_pos[tid];
    #pragma unroll
    for (int r = 0; r < 6; r++){
        int idx = r*256 + tid;          // over 256*6
        int c = idx / 6, j = idx - 6*c;
        wl[1 + j][c] = w_att[idx];
    }
    #pragma unroll
    for (int r = 0; r < 12; r++){
        int idx = r*256 + tid;          // over 256*12
        int c = idx / 12, j = idx - 12*c;
        wl[7 + j][c] = w_img[idx];
    }
    __syncthreads();

    #pragma unroll
    for (int qi = 0; qi < 2; qi++){
        int ql = wid*2 + qi;
        int q  = q0 + ql;

        const float4 a4 = *(const float4*)(bq  + (size_t)q*CCH + c0);
        const float4 b4 = *(const float4*)(bpos+ (size_t)q*CCH + c0);
        float qv[4] = {a4.x+b4.x, a4.y+b4.y, a4.z+b4.z, a4.w+b4.w};

        float s[19];
        #pragma unroll
        for (int j = 0; j < 19; j++){
            const float4 wv = *(const float4*)&wl[j][c0];
            s[j] = qv[0]*wv.x + qv[1]*wv.y + qv[2]*wv.z + qv[3]*wv.w;
        }
        #pragma unroll
        for (int off=1; off<64; off<<=1){
            #pragma unroll
            for (int i=0;i<19;i++) s[i] += __shfl_xor(s[i], off, 64);
        }

        float pos_off = s[0] + b_pos[0];
        float rx = refp[q*3+0], ry = refp[q*3+1], rz = refp[q*3+2];
        float zc_ = fminf(fmaxf(rz, 0.f), 1.f);
        float inv = logf(fmaxf(zc_, EPSV) / fmaxf(1.f - zc_, EPSV));
        float znew = sigmoidf_(inv + pos_off);

        if (lane == 0){
            out_rp[q*3+0] = rx; out_rp[q*3+1] = ry; out_rp[q*3+2] = znew;
        }
        if (lane < NCAM){
            int n = lane;
            float att  = s[1+n] + b_att[n];
            float offx = (s[7+2*n]   + b_img[2*n])   / (float)WFD;
            float offy = (s[7+2*n+1] + b_img[2*n+1]) / (float)HFD;
            float lo0=pcr[0], lo1=pcr[1], lo2=pcr[2];
            float hi0=pcr[3], hi1=pcr[4], hi2=pcr[5];
            float px = rx*(hi0-lo0)+lo0, py = ry*(hi1-lo1)+lo1, pz = znew*(hi2-lo2)+lo2;
            const float* M = l2i + n*16;
            float cx = M[0]*px + M[1]*py + M[2]*pz  + M[3];
            float cy = M[4]*px + M[5]*py + M[6]*pz  + M[7];
            float cz = M[8]*px + M[9]*py + M[10]*pz + M[11];
            bool m = cz > EPSV;
            float zdiv = fmaxf(cz, EPSV);
            float u = (cx/zdiv)/IMGW; u = (u - 0.5f)*2.f;
            float v = (cy/zdiv)/IMGH; v = (v - 0.5f)*2.f;
            m = m && (u > -1.f) && (u < 1.f) && (v > -1.f) && (v < 1.f);
            float rdn = (cz/(float)DDD - 0.5f)*2.f;
            m = m && (rdn > -1.f) && (rdn < 1.f);

            int base = ql*24 + n*4;
            float wq = 0.f, xs = 0.f, ys = 0.f;
            if (m){
                float u2 = u + offx, v2 = v + offy;
                xs = (u2 + 1.f)*0.5f*WFD - 0.5f;
                ys = (v2 + 1.f)*0.5f*HFD - 0.5f;
                float zs = (rdn + 1.f)*0.5f*DDD - 0.5f;
                float fx = floorf(xs), fy = floorf(ys), fz = floorf(zs);
                int x0=(int)fx, y0=(int)fy, z0=(int)fz;
                float wx = xs-fx, wy = ys-fy, wz = zs-fz;
                float dp = 0.f;
                const float* vol = dpr + (size_t)n*DDD*HFD*WFD;
                #pragma unroll
                for (int dz=0; dz<2; dz++)
                #pragma unroll
                for (int dy=0; dy<2; dy++)
                #pragma unroll
                for (int dx=0; dx<2; dx++){
                    int ix=x0+dx, iy=y0+dy, iz=z0+dz;
                    if (ix>=0 && ix<WFD && iy>=0 && iy<HFD && iz>=0 && iz<DDD){
                        float ww = (dx?wx:1.f-wx)*(dy?wy:1.f-wy)*(dz?wz:1.f-wz);
                        dp += ww * vol[(size_t)(iz*HFD+iy)*WFD + ix];
                    }
                }
                wq = sigmoidf_(att) * dp;
            }
            if (m && wq != 0.f){
                float fx = floorf(xs), fy = floorf(ys);
                int x0=(int)fx, y0=(int)fy;
                float wx = xs-fx, wy = ys-fy;
                float cwv[4] = {(1.f-wx)*(1.f-wy), wx*(1.f-wy), (1.f-wx)*wy, wx*wy};
                int xi[4] = {x0, x0+1, x0, x0+1};
                int yi[4] = {y0, y0, y0+1, y0+1};
                #pragma unroll
                for (int k=0;k<4;k++){
                    bool ok = (xi[k]>=0 && xi[k]<WFD && yi[k]>=0 && yi[k]<HFD);
                    so_l[base+k] = ok ? ((n*HFD + yi[k])*WFD + xi[k]) : 0;
                    sw_l[base+k] = ok ? wq*cwv[k] : 0.f;
                }
            } else {
                #pragma unroll
                for (int k=0;k<4;k++){ so_l[base+k] = 0; sw_l[base+k] = 0.f; }
            }
        }
    }
    __syncthreads();

    // gather phase: wave handles its 2 queries, lane covers 4 channels
    int c4 = lane * 4;
    #pragma unroll
    for (int qi=0; qi<2; qi++){
        int ql = wid*2 + qi;
        float a0=0.f, a1=0.f, a2=0.f, a3=0.f;
        #pragma unroll
        for (int k=0;k<24;k++){
            float w = sw_l[ql*24+k];
            if (w != 0.f){
                us4 v = *(const us4*)(feat_tH + (size_t)so_l[ql*24+k]*CCH + c4);
                a0 += w * bf2f(v.x);
                a1 += w * bf2f(v.y);
                a2 += w * bf2f(v.z);
                a3 += w * bf2f(v.w);
            }
        }
        us4 o; o.x = f2bf(a0); o.y = f2bf(a1); o.z = f2bf(a2); o.w = f2bf(a3);
        *(us4*)(aggH + (size_t)(q0+ql)*CCH + c4) = o;
    }
}

// ================= k_conv2: 3x3 conv + BN + ReLU + SE-sum, kw-folded MFMA =================
// block: 512 thr (8 waves), tile 128 px (full BEV row) x 64 co; stages = 3 kh x 4 ci-chunks
__global__ __launch_bounds__(512, 4) void k_conv2(const unsigned short* __restrict__ aggH,
    const unsigned short* __restrict__ wtH, const float* __restrict__ conv_b,
    const float* __restrict__ bn_g, const float* __restrict__ bn_b,
    const float* __restrict__ bn_m, const float* __restrict__ bn_v,
    float* __restrict__ xN, float* __restrict__ ssum)
{
    __shared__ unsigned short Al[130][72];       // rows: input px w = row-1, w in [-1..128]
    __shared__ unsigned short Bl[3][64][72];     // [kw][co][ci]
    __shared__ float sacc[64];

    int h   = blockIdx.x;           // BEV row
    int co0 = blockIdx.y * 64;
    int tid  = threadIdx.x;
    int lane = tid & 63, wid = tid >> 6;
    int m_wave = (wid & 3) * 32;
    int n_wave = (wid >> 2) * 32;
    int l15 = lane & 15, quad = lane >> 4;

    f4_t acc[2][2];
    #pragma unroll
    for (int i=0;i<2;i++)
    #pragma unroll
    for (int j=0;j<2;j++) acc[i][j] = (f4_t){0.f,0.f,0.f,0.f};

    // staging assignments
    int aw = tid >> 2;              // input px w 0..127 -> Al row aw+1
    int sa = (tid & 3) * 16;        // ci segment (shorts)
    int bco = tid >> 3;             // co 0..63
    int sb  = (tid & 7) * 8;        // ci segment (shorts)

    // init always-zero halo rows + sacc (covered by first barrier)
    if (tid < 8){
        int r = (tid >> 2) ? 129 : 0;
        int sg = (tid & 3) * 16;
        us8 z = (us8){0,0,0,0,0,0,0,0};
        *(us8*)&Al[r][sg]   = z;
        *(us8*)&Al[r][sg+8] = z;
    }
    if (tid < 64) sacc[tid] = 0.f;

    us8 ra0, ra1, rb0, rb1, rb2;
    const us8 z8 = (us8){0,0,0,0,0,0,0,0};

    // stage s: kh = s>>2, ci0 = (s&3)*64
    #define LOADSTAGE(s) { \
        int kh_ = (s) >> 2; int ci0_ = ((s) & 3) << 6; \
        int ph_ = h + kh_ - 1; \
        if (ph_ >= 0 && ph_ < BEVH){ \
            const unsigned short* ap_ = aggH + ((size_t)(ph_*BEVW + aw)*CCH + ci0_ + sa); \
            ra0 = *(const us8*)ap_; ra1 = *(const us8*)(ap_ + 8); \
        } else { ra0 = z8; ra1 = z8; } \
        const unsigned short* bp_ = wtH + ((size_t)(kh_*3*256) + co0 + bco)*CCH + ci0_ + sb; \
        rb0 = *(const us8*)bp_; \
        rb1 = *(const us8*)(bp_ + 256*CCH); \
        rb2 = *(const us8*)(bp_ + 512*CCH); \
    }

    LOADSTAGE(0);
    for (int s=0; s<12; s++){
        __syncthreads();
        *(us8*)&Al[aw+1][sa]   = ra0;
        *(us8*)&Al[aw+1][sa+8] = ra1;
        *(us8*)&Bl[0][bco][sb] = rb0;
        *(us8*)&Bl[1][bco][sb] = rb1;
        *(us8*)&Bl[2][bco][sb] = rb2;
        __syncthreads();
        if (s < 11) LOADSTAGE(s+1);
        #pragma unroll
        for (int kw=0; kw<3; kw++){
            #pragma unroll
            for (int ks=0; ks<2; ks++){
                bf8_t af0 = *(bf8_t*)&Al[m_wave      + l15 + kw][ks*32 + quad*8];
                bf8_t af1 = *(bf8_t*)&Al[m_wave + 16 + l15 + kw][ks*32 + quad*8];
                bf8_t bf0 = *(bf8_t*)&Bl[kw][n_wave      + l15][ks*32 + quad*8];
                bf8_t bf1 = *(bf8_t*)&Bl[kw][n_wave + 16 + l15][ks*32 + quad*8];
                acc[0][0] = __builtin_amdgcn_mfma_f32_16x16x32_bf16(af0, bf0, acc[0][0], 0, 0, 0);
                acc[0][1] = __builtin_amdgcn_mfma_f32_16x16x32_bf16(af0, bf1, acc[0][1], 0, 0, 0);
                acc[1][0] = __builtin_amdgcn_mfma_f32_16x16x32_bf16(af1, bf0, acc[1][0], 0, 0, 0);
                acc[1][1] = __builtin_amdgcn_mfma_f32_16x16x32_bf16(af1, bf1, acc[1][1], 0, 0, 0);
            }
        }
    }
    #undef LOADSTAGE

    // epilogue: bias + BN + ReLU, write xN, accumulate SE partial
    #pragma unroll
    for (int j=0;j<2;j++){
        int col = n_wave + j*16 + l15;
        int co = co0 + col;
        float sc = bn_g[co] * rsqrtf(bn_v[co] + 1e-5f);
        float sh = bn_b[co] - bn_m[co]*sc;
        float cb = conv_b[co];
        float part = 0.f;
        #pragma unroll
        for (int i=0;i<2;i++){
            #pragma unroll
            for (int r=0;r<4;r++){
                int m = m_wave + i*16 + quad*4 + r;
                int p = h*BEVW + m;
                float y = fmaxf((acc[i][j][r] + cb)*sc + sh, 0.f);
                xN[(size_t)p*CCH + co] = y;
                part += y;
            }
        }
        atomicAdd(&sacc[col], part);
    }
    __syncthreads();
    if (tid < 64) atomicAdd(&ssum[co0 + tid], sacc[tid]);
}

// ================= k_maps2: SE scale (recomputed per block) + CBAM channel maps =================
__global__ __launch_bounds__(256) void k_maps2(const float* __restrict__ xN,
    const float* __restrict__ ssum, const float* __restrict__ se_w, const float* __restrict__ se_b,
    float* __restrict__ scale_g, float* __restrict__ amax, float* __restrict__ amean)
{
    __shared__ float smv[256];
    __shared__ float scl[256];
    int t = threadIdx.x;
    smv[t] = ssum[t] * (1.f/16384.f);
    __syncthreads();
    float acc = se_b[t];
    for (int k=0; k<256; k+=4){
        float4 w4 = *(const float4*)&se_w[(size_t)t*256 + k];
        acc += smv[k]*w4.x + smv[k+1]*w4.y + smv[k+2]*w4.z + smv[k+3]*w4.w;
    }
    float sv = sigmoidf_(acc);
    scl[t] = sv;
    if (blockIdx.x == 0) scale_g[t] = sv;
    __syncthreads();

    int wid = t >> 6, lane = t & 63;
    int p0 = blockIdx.x * 64;
    float4 sc = *(const float4*)&scl[lane*4];
    for (int i=0; i<16; i++){
        int p = p0 + i*4 + wid;
        float4 v = *(const float4*)&xN[(size_t)p*CCH + lane*4];
        float a = v.x*sc.x, b = v.y*sc.y, c = v.z*sc.z, d = v.w*sc.w;
        float mx = fmaxf(fmaxf(a,b), fmaxf(c,d));
        float sm = a+b+c+d;
        #pragma unroll
        for (int off=1; off<64; off<<=1){
            mx = fmaxf(mx, __shfl_xor(mx, off, 64));
            sm += __shfl_xor(sm, off, 64);
        }
        if (lane == 0){ amax[p] = mx; amean[p] = sm*(1.f/256.f); }
    }
}

// ================= k_final2: CBAM 7x7 (in-block) + final scaling =================
__global__ __launch_bounds__(256) void k_final2(const float* __restrict__ xN,
    const float* __restrict__ scale_g, const float* __restrict__ amax, const float* __restrict__ amean,
    const float* __restrict__ cw, const float* __restrict__ cb, float* __restrict__ out)
{
    __shared__ float am2[7][128];
    __shared__ float av2[7][128];
    __shared__ float wcb[98];
    __shared__ float scl[256];
    __shared__ float amap_l[64];

    int b = blockIdx.x;
    int h  = b >> 1;
    int w0 = (b & 1) * 64;
    int t = threadIdx.x;

    scl[t] = scale_g[t];
    if (t < 98) wcb[t] = cw[t];
    for (int idx = t; idx < 896; idx += 256){
        int r = idx >> 7, c = idx & 127;
        int ph = h + r - 3;
        bool ok = (ph >= 0 && ph < BEVH);
        am2[r][c] = ok ? amax[ph*BEVW + c] : 0.f;
        av2[r][c] = ok ? amean[ph*BEVW + c] : 0.f;
    }
    __syncthreads();

    if (t < 64){
        int px = w0 + t;
        float acc = cb[0];
        #pragma unroll
        for (int kh=0; kh<7; kh++){
            #pragma unroll
            for (int kw=0; kw<7; kw++){
                int pw = px + kw - 3;
                if (pw >= 0 && pw < BEVW)
                    acc += am2[kh][pw]*wcb[kh*7+kw] + av2[kh][pw]*wcb[49 + kh*7+kw];
            }
        }
        amap_l[t] = sigmoidf_(acc);
    }
    __syncthreads();

    int lane = t & 63, sub = t >> 6;
    int c4 = lane * 4;
    float4 sc = *(const float4*)&scl[c4];
    for (int i=0; i<16; i++){
        int pxl = sub*16 + i;
        int p = h*BEVW + w0 + pxl;
        float am = amap_l[pxl];
        float4 v = *(const float4*)&xN[(size_t)p*CCH + c4];
        float4 o;
        o.x = v.x*sc.x*am; o.y = v.y*sc.y*am; o.z = v.z*sc.z*am; o.w = v.w*sc.w*am;
        *(float4*)&out[(size_t)p*CCH + c4] = o;
    }
}

extern "C" void kernel_launch(void* const* d_in, const int* in_sizes, int n_in,
                              void* d_out, int out_size, void* d_ws, size_t ws_size,
                              hipStream_t stream) {
    const float* feat   = (const float*)d_in[0];
    const float* bq     = (const float*)d_in[1];
    const float* bpos   = (const float*)d_in[2];
    const float* refp   = (const float*)d_in[3];
    const float* pcr    = (const float*)d_in[4];
    const float* l2i    = (const float*)d_in[5];
    const float* dpr    = (const float*)d_in[6];
    const float* w_pos  = (const float*)d_in[7];
    const float* b_pos  = (const float*)d_in[8];
    const float* w_img  = (const float*)d_in[9];
    const float* b_img  = (const float*)d_in[10];
    const float* w_att  = (const float*)d_in[11];
    const float* b_att  = (const float*)d_in[12];
    const float* conv_w = (const float*)d_in[13];
    const float* conv_b = (const float*)d_in[14];
    const float* bn_g   = (const float*)d_in[15];
    const float* bn_b   = (const float*)d_in[16];
    const float* bn_m   = (const float*)d_in[17];
    const float* bn_v   = (const float*)d_in[18];
    const float* se_w   = (const float*)d_in[19];
    const float* se_b   = (const float*)d_in[20];
    const float* cbw    = (const float*)d_in[21];
    const float* cbb    = (const float*)d_in[22];
    float* out = (float*)d_out;

    float* ws = (float*)d_ws;
    size_t o = 0;
    unsigned short* feat_tH = (unsigned short*)(ws + o); o += (size_t)6*2816*128;  // bf16
    unsigned short* wtH  = (unsigned short*)(ws + o); o += (size_t)9*256*128;      // bf16
    unsigned short* aggH = (unsigned short*)(ws + o); o += (size_t)QN*128;         // bf16
    float* xN      = ws + o;  o += (size_t)QN*256;
    float* ssum    = ws + o;  o += 256;
    float* scale_g = ws + o;  o += 256;
    float* amax    = ws + o;  o += QN;
    float* amean   = ws + o;  o += QN;

    k_prep<<<6528, 256, 0, stream>>>(feat, feat_tH, conv_w, wtH, ssum);
    k_geomagg<<<2048, 256, 0, stream>>>(bq, bpos, refp, pcr, l2i, dpr,
                                        w_pos, b_pos, w_img, b_img, w_att, b_att,
                                        feat_tH, aggH, out + (size_t)QN*256);
    k_conv2<<<dim3(128,4), 512, 0, stream>>>(aggH, wtH, conv_b, bn_g, bn_b, bn_m, bn_v, xN, ssum);
    k_maps2<<<256, 256, 0, stream>>>(xN, ssum, se_w, se_b, scale_g, amax, amean);
    k_final2<<<256, 256, 0, stream>>>(xN, scale_g, amax, amean, cbw, cbb, out);
}

// Round 6
// 238.472 us; speedup vs baseline: 1.1098x; 1.0319x over previous
//
#include <hip/hip_runtime.h>
#include <math.h>

#define QN   16384
#define CCH  256
#define NCAM 6
#define HFD  32
#define WFD  88
#define DDD  64
#define BEVH 128
#define BEVW 128
#define IMGW 704.0f
#define IMGH 256.0f
#define EPSV 1e-5f

typedef __attribute__((ext_vector_type(8))) short bf8_t;    // 8 bf16 (MFMA operand)
typedef __attribute__((ext_vector_type(8))) unsigned short us8;
typedef __attribute__((ext_vector_type(4))) unsigned short us4;
typedef __attribute__((ext_vector_type(4))) float f4_t;

__device__ __forceinline__ float sigmoidf_(float x){ return 1.0f/(1.0f+__expf(-x)); }

__device__ __forceinline__ unsigned short f2bf(float f){
    unsigned int b = __float_as_uint(f);
    b += 0x7FFFu + ((b >> 16) & 1u);
    return (unsigned short)(b >> 16);
}
__device__ __forceinline__ float bf2f(unsigned short u){
    return __uint_as_float(((unsigned int)u) << 16);
}

// ================= k_prep: feat transpose + weight pack + se_w transpose + ssum zero =================
// blocks [0,4224): feat (6,256,32,88) f32 -> feat_tH (6,2816,256) bf16
// blocks [4224,6528): conv_w -> wtH bf16 stage-major [s=kh*4+cichunk][kw][co][ci64]
// blocks [6528,6592): se_w (t,k) -> se_wT (k,t)
__global__ __launch_bounds__(256) void k_prep(const float* __restrict__ feat, unsigned short* __restrict__ feat_tH,
                                              const float* __restrict__ cw, unsigned short* __restrict__ wtH,
                                              const float* __restrict__ se_w, float* __restrict__ se_wT,
                                              float* __restrict__ ssum){
    int b = blockIdx.x;
    if (b < 4224){
        __shared__ float tile[32][33];
        int n   = b / 704;          // 88*8 = 704
        int rem = b - n*704;
        int cb  = (rem / 88) * 32;
        int pb  = (rem % 88) * 32;
        int tx = threadIdx.x & 31, ty = threadIdx.x >> 5;
        for (int r = ty; r < 32; r += 8)
            tile[r][tx] = feat[(size_t)(n*256 + cb + r)*2816 + pb + tx];
        __syncthreads();
        for (int r = ty; r < 32; r += 8)
            feat_tH[(size_t)(n*2816 + pb + r)*256 + cb + tx] = f2bf(tile[tx][r]);
    } else if (b < 6528){
        int b2 = b - 4224;
        if (b2 == 0) ssum[threadIdx.x] = 0.f;
        int idx = b2*256 + threadIdx.x;     // < 9*256*256 exactly
        int ci = idx & 255;
        int co = (idx >> 8) & 255;
        int kk = idx >> 16;
        int kh = kk/3, kw = kk - kh*3;
        int chunk = ci >> 6, ciin = ci & 63;
        size_t dst = ((((size_t)(kh*4 + chunk)*3 + kw)*256 + co) << 6) + ciin;
        wtH[dst] = f2bf(cw[(size_t)(co*256 + ci)*9 + kk]);
    } else {
        __shared__ float tile[32][33];
        int tb = b - 6528;                  // 0..63
        int rb_ = (tb >> 3) * 32;           // over t (rows of se_w)
        int cb_ = (tb & 7) * 32;            // over k
        int tx = threadIdx.x & 31, ty = threadIdx.x >> 5;
        for (int r = ty; r < 32; r += 8)
            tile[r][tx] = se_w[(size_t)(rb_ + r)*256 + cb_ + tx];
        __syncthreads();
        for (int r = ty; r < 32; r += 8)
            se_wT[(size_t)(cb_ + r)*256 + rb_ + tx] = tile[tx][r];
    }
}

// ================= k_geomagg: fused geometry + feature aggregation =================
// 2048 blocks x 256 thr; block = 8 queries, wave = 2 queries
// v6: (a) s-values passed via LDS (no dynamic reg-index), geometry for both queries
//     of a wave runs in parallel on lanes 0-5 / 32-37; (b) gather phase uses us8
//     (16B/lane) with lane halves covering the wave's two queries (24 vmem vs 48).
__global__ __launch_bounds__(256) void k_geomagg(
    const float* __restrict__ bq, const float* __restrict__ bpos,
    const float* __restrict__ refp, const float* __restrict__ pcr,
    const float* __restrict__ l2i, const float* __restrict__ dpr,
    const float* __restrict__ w_pos, const float* __restrict__ b_pos,
    const float* __restrict__ w_img, const float* __restrict__ b_img,
    const float* __restrict__ w_att, const float* __restrict__ b_att,
    const unsigned short* __restrict__ feat_tH,
    unsigned short* __restrict__ aggH, float* __restrict__ out_rp)
{
    __shared__ float wl[19][256];   // [j][c]: 0=pos, 1..6=att, 7..18=img
    __shared__ float sprj[8][24];   // per query: 0..18 = s[j], 19=znew, 20=rx, 21=ry
    __shared__ int   so_l[192];
    __shared__ float sw_l[192];
    int q0 = blockIdx.x * 8;
    int tid = threadIdx.x;
    int wid = tid >> 6, lane = tid & 63;
    int c0 = lane * 4;

    // ---- stage projection weights ----
    wl[0][tid] = w_pos[tid];
    #pragma unroll
    for (int r = 0; r < 6; r++){
        int idx = r*256 + tid;
        int c = idx / 6, j = idx - 6*c;
        wl[1 + j][c] = w_att[idx];
    }
    #pragma unroll
    for (int r = 0; r < 12; r++){
        int idx = r*256 + tid;
        int c = idx / 12, j = idx - 12*c;
        wl[7 + j][c] = w_img[idx];
    }
    __syncthreads();

    // ---- phase 1: projections (per wave: 2 queries) ----
    #pragma unroll
    for (int qi = 0; qi < 2; qi++){
        int ql = wid*2 + qi;
        int q  = q0 + ql;

        const float4 a4 = *(const float4*)(bq  + (size_t)q*CCH + c0);
        const float4 b4 = *(const float4*)(bpos+ (size_t)q*CCH + c0);
        float qv[4] = {a4.x+b4.x, a4.y+b4.y, a4.z+b4.z, a4.w+b4.w};

        float s[19];
        #pragma unroll
        for (int j = 0; j < 19; j++){
            const float4 wv = *(const float4*)&wl[j][c0];
            s[j] = qv[0]*wv.x + qv[1]*wv.y + qv[2]*wv.z + qv[3]*wv.w;
        }
        #pragma unroll
        for (int off=1; off<64; off<<=1){
            #pragma unroll
            for (int i=0;i<19;i++) s[i] += __shfl_xor(s[i], off, 64);
        }

        if (lane == 0){
            float pos_off = s[0] + b_pos[0];
            float rx = refp[q*3+0], ry = refp[q*3+1], rz = refp[q*3+2];
            float zc_ = fminf(fmaxf(rz, 0.f), 1.f);
            float inv = logf(fmaxf(zc_, EPSV) / fmaxf(1.f - zc_, EPSV));
            float znew = sigmoidf_(inv + pos_off);
            out_rp[q*3+0] = rx; out_rp[q*3+1] = ry; out_rp[q*3+2] = znew;
            #pragma unroll
            for (int j=0;j<19;j++) sprj[ql][j] = s[j];
            sprj[ql][19] = znew; sprj[ql][20] = rx; sprj[ql][21] = ry;
        }
    }
    __syncthreads();

    // ---- phase 2: per-camera geometry, both queries of the wave in parallel ----
    {
        int sub = lane >> 5;        // 0: even query, 1: odd query
        int n   = lane & 31;        // camera
        if (n < NCAM){
            int ql = wid*2 + sub;
            float att  = sprj[ql][1+n] + b_att[n];
            float offx = (sprj[ql][7+2*n] + b_img[2*n])   / (float)WFD;
            float offy = (sprj[ql][8+2*n] + b_img[2*n+1]) / (float)HFD;
            float znew = sprj[ql][19], rx = sprj[ql][20], ry = sprj[ql][21];
            float lo0=pcr[0], lo1=pcr[1], lo2=pcr[2];
            float hi0=pcr[3], hi1=pcr[4], hi2=pcr[5];
            float px = rx*(hi0-lo0)+lo0, py = ry*(hi1-lo1)+lo1, pz = znew*(hi2-lo2)+lo2;
            const float* M = l2i + n*16;
            float cx = M[0]*px + M[1]*py + M[2]*pz  + M[3];
            float cy = M[4]*px + M[5]*py + M[6]*pz  + M[7];
            float cz = M[8]*px + M[9]*py + M[10]*pz + M[11];
            bool m = cz > EPSV;
            float zdiv = fmaxf(cz, EPSV);
            float u = (cx/zdiv)/IMGW; u = (u - 0.5f)*2.f;
            float v = (cy/zdiv)/IMGH; v = (v - 0.5f)*2.f;
            m = m && (u > -1.f) && (u < 1.f) && (v > -1.f) && (v < 1.f);
            float rdn = (cz/(float)DDD - 0.5f)*2.f;
            m = m && (rdn > -1.f) && (rdn < 1.f);

            int base = ql*24 + n*4;
            float wq = 0.f, xs = 0.f, ys = 0.f;
            if (m){
                float u2 = u + offx, v2 = v + offy;
                xs = (u2 + 1.f)*0.5f*WFD - 0.5f;
                ys = (v2 + 1.f)*0.5f*HFD - 0.5f;
                float zs = (rdn + 1.f)*0.5f*DDD - 0.5f;
                float fx = floorf(xs), fy = floorf(ys), fz = floorf(zs);
                int x0=(int)fx, y0=(int)fy, z0=(int)fz;
                float wx = xs-fx, wy = ys-fy, wz = zs-fz;
                float dp = 0.f;
                const float* vol = dpr + (size_t)n*DDD*HFD*WFD;
                #pragma unroll
                for (int dz=0; dz<2; dz++)
                #pragma unroll
                for (int dy=0; dy<2; dy++)
                #pragma unroll
                for (int dx=0; dx<2; dx++){
                    int ix=x0+dx, iy=y0+dy, iz=z0+dz;
                    if (ix>=0 && ix<WFD && iy>=0 && iy<HFD && iz>=0 && iz<DDD){
                        float ww = (dx?wx:1.f-wx)*(dy?wy:1.f-wy)*(dz?wz:1.f-wz);
                        dp += ww * vol[(size_t)(iz*HFD+iy)*WFD + ix];
                    }
                }
                wq = sigmoidf_(att) * dp;
            }
            if (m && wq != 0.f){
                float fx = floorf(xs), fy = floorf(ys);
                int x0=(int)fx, y0=(int)fy;
                float wx = xs-fx, wy = ys-fy;
                float cwv[4] = {(1.f-wx)*(1.f-wy), wx*(1.f-wy), (1.f-wx)*wy, wx*wy};
                int xi[4] = {x0, x0+1, x0, x0+1};
                int yi[4] = {y0, y0, y0+1, y0+1};
                #pragma unroll
                for (int k=0;k<4;k++){
                    bool ok = (xi[k]>=0 && xi[k]<WFD && yi[k]>=0 && yi[k]<HFD);
                    so_l[base+k] = ok ? ((n*HFD + yi[k])*WFD + xi[k]) : 0;
                    sw_l[base+k] = ok ? wq*cwv[k] : 0.f;
                }
            } else {
                #pragma unroll
                for (int k=0;k<4;k++){ so_l[base+k] = 0; sw_l[base+k] = 0.f; }
            }
        }
    }
    __syncthreads();

    // ---- phase 3: gather; lane halves cover the wave's two queries, 8 ch/lane ----
    {
        int half = lane >> 5, li = lane & 31;
        int c8 = li * 8;
        int ql = wid*2 + half;
        float a[8] = {0.f,0.f,0.f,0.f,0.f,0.f,0.f,0.f};
        #pragma unroll
        for (int k=0;k<24;k++){
            float w = sw_l[ql*24+k];
            if (w != 0.f){
                us8 v = *(const us8*)(feat_tH + (size_t)so_l[ql*24+k]*CCH + c8);
                #pragma unroll
                for (int j=0;j<8;j++) a[j] += w * bf2f((unsigned short)v[j]);
            }
        }
        us8 o;
        #pragma unroll
        for (int j=0;j<8;j++) o[j] = f2bf(a[j]);
        *(us8*)(aggH + (size_t)(q0+ql)*CCH + c8) = o;
    }
}

// ================= k_conv2: 3x3 conv + BN + ReLU + SE-sum, kw-folded MFMA =================
// v6: block 256 thr (4 waves), tile 128 px (full BEV row) x 128 co, wave tile 64x64
// (0.5 LDS-reads/MFMA), stage-contiguous wtH, full register prefetch.
__global__ __launch_bounds__(256, 2) void k_conv2(const unsigned short* __restrict__ aggH,
    const unsigned short* __restrict__ wtH, const float* __restrict__ conv_b,
    const float* __restrict__ bn_g, const float* __restrict__ bn_b,
    const float* __restrict__ bn_m, const float* __restrict__ bn_v,
    float* __restrict__ xN, float* __restrict__ ssum)
{
    __shared__ unsigned short Al[130][72];       // rows: input px w = row-1
    __shared__ unsigned short Bl[3][128][72];    // [kw][co][ci]
    __shared__ float sacc[128];

    int h   = blockIdx.x;           // BEV row
    int co0 = blockIdx.y * 128;
    int tid  = threadIdx.x;
    int lane = tid & 63, wid = tid >> 6;
    int m_q = (wid & 1) * 64;
    int n_q = (wid >> 1) * 64;
    int l15 = lane & 15, quad = lane >> 4;

    f4_t acc[4][4];
    #pragma unroll
    for (int i=0;i<4;i++)
    #pragma unroll
    for (int j=0;j<4;j++) acc[i][j] = (f4_t){0.f,0.f,0.f,0.f};

    // staging assignments
    int arow = tid >> 1;            // input px w 0..127 -> Al row arow+1
    int aseg = (tid & 1) * 32;      // ci segment start (shorts), 4x us8

    // halo columns (w=-1, w=128) are always zero; init once
    if (tid < 16){
        int r = (tid >> 3) ? 129 : 0;
        int sg = (tid & 7) * 8;
        *(us8*)&Al[r][sg] = (us8){0,0,0,0,0,0,0,0};
    }
    if (tid < 128) sacc[tid] = 0.f;

    us8 ra[4], rb[3][4];
    const us8 z8 = (us8){0,0,0,0,0,0,0,0};

    // stage s: kh = s>>2, ci0 = (s&3)*64; wtH stage-major: base = s*49152
    #define LOADSTAGE(s) { \
        int kh_ = (s) >> 2; int ci0_ = ((s) & 3) << 6; \
        int ph_ = h + kh_ - 1; \
        if (ph_ >= 0 && ph_ < BEVH){ \
            const unsigned short* ap_ = aggH + ((size_t)(ph_*BEVW + arow)*CCH + ci0_ + aseg); \
            ra[0] = *(const us8*)ap_;      ra[1] = *(const us8*)(ap_ + 8); \
            ra[2] = *(const us8*)(ap_ + 16); ra[3] = *(const us8*)(ap_ + 24); \
        } else { ra[0]=z8; ra[1]=z8; ra[2]=z8; ra[3]=z8; } \
        const unsigned short* bp_ = wtH + (size_t)(s)*49152 + (size_t)co0*64; \
        _Pragma("unroll") \
        for (int kw_=0; kw_<3; kw_++){ \
            _Pragma("unroll") \
            for (int j_=0; j_<4; j_++) \
                rb[kw_][j_] = *(const us8*)(bp_ + kw_*16384 + (j_*256 + tid)*8); \
        } \
    }

    LOADSTAGE(0);
    for (int s=0; s<12; s++){
        __syncthreads();
        *(us8*)&Al[arow+1][aseg]      = ra[0];
        *(us8*)&Al[arow+1][aseg+8]    = ra[1];
        *(us8*)&Al[arow+1][aseg+16]   = ra[2];
        *(us8*)&Al[arow+1][aseg+24]   = ra[3];
        {
            int bco = tid >> 3;             // base co row within 32-co group
            int ciin = (tid & 7) * 8;
            #pragma unroll
            for (int kw_=0; kw_<3; kw_++){
                #pragma unroll
                for (int j_=0; j_<4; j_++)
                    *(us8*)&Bl[kw_][j_*32 + bco][ciin] = rb[kw_][j_];
            }
        }
        __syncthreads();
        if (s < 11) LOADSTAGE(s+1);
        #pragma unroll
        for (int ks=0; ks<2; ks++){
            #pragma unroll
            for (int kw=0; kw<3; kw++){
                bf8_t af[4], bfr[4];
                #pragma unroll
                for (int i=0;i<4;i++) af[i]  = *(bf8_t*)&Al[m_q + i*16 + l15 + kw][ks*32 + quad*8];
                #pragma unroll
                for (int j=0;j<4;j++) bfr[j] = *(bf8_t*)&Bl[kw][n_q + j*16 + l15][ks*32 + quad*8];
                #pragma unroll
                for (int i=0;i<4;i++)
                #pragma unroll
                for (int j=0;j<4;j++)
                    acc[i][j] = __builtin_amdgcn_mfma_f32_16x16x32_bf16(af[i], bfr[j], acc[i][j], 0, 0, 0);
            }
        }
    }
    #undef LOADSTAGE

    // epilogue: bias + BN + ReLU, write xN, accumulate SE partial
    #pragma unroll
    for (int j=0;j<4;j++){
        int col = n_q + j*16 + l15;
        int co = co0 + col;
        float sc = bn_g[co] * rsqrtf(bn_v[co] + 1e-5f);
        float sh = bn_b[co] - bn_m[co]*sc;
        float cb = conv_b[co];
        float part = 0.f;
        #pragma unroll
        for (int i=0;i<4;i++){
            #pragma unroll
            for (int r=0;r<4;r++){
                int m = m_q + i*16 + quad*4 + r;
                int p = h*BEVW + m;
                float y = fmaxf((acc[i][j][r] + cb)*sc + sh, 0.f);
                xN[(size_t)p*CCH + co] = y;
                part += y;
            }
        }
        atomicAdd(&sacc[col], part);
    }
    __syncthreads();
    if (tid < 128) atomicAdd(&ssum[co0 + tid], sacc[tid]);
}

// ================= k_maps2: SE scale (coalesced via se_wT) + CBAM channel maps =================
__global__ __launch_bounds__(256) void k_maps2(const float* __restrict__ xN,
    const float* __restrict__ ssum, const float* __restrict__ se_wT, const float* __restrict__ se_b,
    float* __restrict__ scale_g, float* __restrict__ amax, float* __restrict__ amean)
{
    __shared__ float smv[256];
    __shared__ float scl[256];
    int t = threadIdx.x;
    smv[t] = ssum[t] * (1.f/16384.f);
    __syncthreads();
    float a0=0.f, a1=0.f, a2=0.f, a3=0.f;
    for (int k=0; k<256; k+=4){
        a0 += smv[k]   * se_wT[(size_t)(k  )*256 + t];
        a1 += smv[k+1] * se_wT[(size_t)(k+1)*256 + t];
        a2 += smv[k+2] * se_wT[(size_t)(k+2)*256 + t];
        a3 += smv[k+3] * se_wT[(size_t)(k+3)*256 + t];
    }
    float sv = sigmoidf_(se_b[t] + ((a0+a1)+(a2+a3)));
    scl[t] = sv;
    if (blockIdx.x == 0) scale_g[t] = sv;
    __syncthreads();

    int wid = t >> 6, lane = t & 63;
    int p0 = blockIdx.x * 64;
    float4 sc = *(const float4*)&scl[lane*4];
    for (int i=0; i<16; i++){
        int p = p0 + i*4 + wid;
        float4 v = *(const float4*)&xN[(size_t)p*CCH + lane*4];
        float a = v.x*sc.x, b = v.y*sc.y, c = v.z*sc.z, d = v.w*sc.w;
        float mx = fmaxf(fmaxf(a,b), fmaxf(c,d));
        float sm = a+b+c+d;
        #pragma unroll
        for (int off=1; off<64; off<<=1){
            mx = fmaxf(mx, __shfl_xor(mx, off, 64));
            sm += __shfl_xor(sm, off, 64);
        }
        if (lane == 0){ amax[p] = mx; amean[p] = sm*(1.f/256.f); }
    }
}

// ================= k_final2: CBAM 7x7 (in-block) + final scaling =================
__global__ __launch_bounds__(256) void k_final2(const float* __restrict__ xN,
    const float* __restrict__ scale_g, const float* __restrict__ amax, const float* __restrict__ amean,
    const float* __restrict__ cw, const float* __restrict__ cb, float* __restrict__ out)
{
    __shared__ float am2[7][128];
    __shared__ float av2[7][128];
    __shared__ float wcb[98];
    __shared__ float scl[256];
    __shared__ float amap_l[64];

    int b = blockIdx.x;
    int h  = b >> 1;
    int w0 = (b & 1) * 64;
    int t = threadIdx.x;

    scl[t] = scale_g[t];
    if (t < 98) wcb[t] = cw[t];
    for (int idx = t; idx < 896; idx += 256){
        int r = idx >> 7, c = idx & 127;
        int ph = h + r - 3;
        bool ok = (ph >= 0 && ph < BEVH);
        am2[r][c] = ok ? amax[ph*BEVW + c] : 0.f;
        av2[r][c] = ok ? amean[ph*BEVW + c] : 0.f;
    }
    __syncthreads();

    if (t < 64){
        int px = w0 + t;
        float acc = cb[0];
        #pragma unroll
        for (int kh=0; kh<7; kh++){
            #pragma unroll
            for (int kw=0; kw<7; kw++){
                int pw = px + kw - 3;
                if (pw >= 0 && pw < BEVW)
                    acc += am2[kh][pw]*wcb[kh*7+kw] + av2[kh][pw]*wcb[49 + kh*7+kw];
            }
        }
        amap_l[t] = sigmoidf_(acc);
    }
    __syncthreads();

    int lane = t & 63, sub = t >> 6;
    int c4 = lane * 4;
    float4 sc = *(const float4*)&scl[c4];
    for (int i=0; i<16; i++){
        int pxl = sub*16 + i;
        int p = h*BEVW + w0 + pxl;
        float am = amap_l[pxl];
        float4 v = *(const float4*)&xN[(size_t)p*CCH + c4];
        float4 o;
        o.x = v.x*sc.x*am; o.y = v.y*sc.y*am; o.z = v.z*sc.z*am; o.w = v.w*sc.w*am;
        *(float4*)&out[(size_t)p*CCH + c4] = o;
    }
}

extern "C" void kernel_launch(void* const* d_in, const int* in_sizes, int n_in,
                              void* d_out, int out_size, void* d_ws, size_t ws_size,
                              hipStream_t stream) {
    const float* feat   = (const float*)d_in[0];
    const float* bq     = (const float*)d_in[1];
    const float* bpos   = (const float*)d_in[2];
    const float* refp   = (const float*)d_in[3];
    const float* pcr    = (const float*)d_in[4];
    const float* l2i    = (const float*)d_in[5];
    const float* dpr    = (const float*)d_in[6];
    const float* w_pos  = (const float*)d_in[7];
    const float* b_pos  = (const float*)d_in[8];
    const float* w_img  = (const float*)d_in[9];
    const float* b_img  = (const float*)d_in[10];
    const float* w_att  = (const float*)d_in[11];
    const float* b_att  = (const float*)d_in[12];
    const float* conv_w = (const float*)d_in[13];
    const float* conv_b = (const float*)d_in[14];
    const float* bn_g   = (const float*)d_in[15];
    const float* bn_b   = (const float*)d_in[16];
    const float* bn_m   = (const float*)d_in[17];
    const float* bn_v   = (const float*)d_in[18];
    const float* se_w   = (const float*)d_in[19];
    const float* se_b   = (const float*)d_in[20];
    const float* cbw    = (const float*)d_in[21];
    const float* cbb    = (const float*)d_in[22];
    float* out = (float*)d_out;

    float* ws = (float*)d_ws;
    size_t o = 0;
    unsigned short* feat_tH = (unsigned short*)(ws + o); o += (size_t)6*2816*128;  // bf16
    unsigned short* wtH  = (unsigned short*)(ws + o); o += (size_t)9*256*128;      // bf16
    unsigned short* aggH = (unsigned short*)(ws + o); o += (size_t)QN*128;         // bf16
    float* xN      = ws + o;  o += (size_t)QN*256;
    float* se_wT   = ws + o;  o += (size_t)256*256;
    float* ssum    = ws + o;  o += 256;
    float* scale_g = ws + o;  o += 256;
    float* amax    = ws + o;  o += QN;
    float* amean   = ws + o;  o += QN;

    k_prep<<<6592, 256, 0, stream>>>(feat, feat_tH, conv_w, wtH, se_w, se_wT, ssum);
    k_geomagg<<<2048, 256, 0, stream>>>(bq, bpos, refp, pcr, l2i, dpr,
                                        w_pos, b_pos, w_img, b_img, w_att, b_att,
                                        feat_tH, aggH, out + (size_t)QN*256);
    k_conv2<<<dim3(128,2), 256, 0, stream>>>(aggH, wtH, conv_b, bn_g, bn_b, bn_m, bn_v, xN, ssum);
    k_maps2<<<256, 256, 0, stream>>>(xN, ssum, se_wT, se_b, scale_g, amax, amean);
    k_final2<<<256, 256, 0, stream>>>(xN, scale_g, amax, amean, cbw, cbb, out);
}

// Round 7
// 221.898 us; speedup vs baseline: 1.1927x; 1.0747x over previous
//
#include <hip/hip_runtime.h>
#include <math.h>

#define QN   16384
#define CCH  256
#define NCAM 6
#define HFD  32
#define WFD  88
#define DDD  64
#define BEVH 128
#define BEVW 128
#define IMGW 704.0f
#define IMGH 256.0f
#define EPSV 1e-5f

typedef __attribute__((ext_vector_type(8))) short bf8_t;    // 8 bf16 (MFMA operand)
typedef __attribute__((ext_vector_type(8))) unsigned short us8;
typedef __attribute__((ext_vector_type(4))) unsigned short us4;
typedef __attribute__((ext_vector_type(4))) float f4_t;

__device__ __forceinline__ float sigmoidf_(float x){ return 1.0f/(1.0f+__expf(-x)); }

__device__ __forceinline__ unsigned short f2bf(float f){
    unsigned int b = __float_as_uint(f);
    b += 0x7FFFu + ((b >> 16) & 1u);
    return (unsigned short)(b >> 16);
}
__device__ __forceinline__ float bf2f(unsigned short u){
    return __uint_as_float(((unsigned int)u) << 16);
}

// ================= k_prep: feat transpose + weight pack + se_w transpose + ssum zero =================
// blocks [0,4224): feat (6,256,32,88) f32 -> feat_tH (6,2816,256) bf16
// blocks [4224,6528): conv_w -> wtH bf16 stage-major [s=kh*4+cichunk][kw][co][ci64]
// blocks [6528,6592): se_w (t,k) -> se_wT (k,t)
__global__ __launch_bounds__(256) void k_prep(const float* __restrict__ feat, unsigned short* __restrict__ feat_tH,
                                              const float* __restrict__ cw, unsigned short* __restrict__ wtH,
                                              const float* __restrict__ se_w, float* __restrict__ se_wT,
                                              float* __restrict__ ssum){
    int b = blockIdx.x;
    if (b < 4224){
        __shared__ float tile[32][33];
        int n   = b / 704;          // 88*8 = 704
        int rem = b - n*704;
        int cb  = (rem / 88) * 32;
        int pb  = (rem % 88) * 32;
        int tx = threadIdx.x & 31, ty = threadIdx.x >> 5;
        for (int r = ty; r < 32; r += 8)
            tile[r][tx] = feat[(size_t)(n*256 + cb + r)*2816 + pb + tx];
        __syncthreads();
        for (int r = ty; r < 32; r += 8)
            feat_tH[(size_t)(n*2816 + pb + r)*256 + cb + tx] = f2bf(tile[tx][r]);
    } else if (b < 6528){
        int b2 = b - 4224;
        if (b2 == 0) ssum[threadIdx.x] = 0.f;
        int idx = b2*256 + threadIdx.x;     // < 9*256*256 exactly
        int ci = idx & 255;
        int co = (idx >> 8) & 255;
        int kk = idx >> 16;
        int kh = kk/3, kw = kk - kh*3;
        int chunk = ci >> 6, ciin = ci & 63;
        size_t dst = ((((size_t)(kh*4 + chunk)*3 + kw)*256 + co) << 6) + ciin;
        wtH[dst] = f2bf(cw[(size_t)(co*256 + ci)*9 + kk]);
    } else {
        __shared__ float tile[32][33];
        int tb = b - 6528;                  // 0..63
        int rb_ = (tb >> 3) * 32;           // over t (rows of se_w)
        int cb_ = (tb & 7) * 32;            // over k
        int tx = threadIdx.x & 31, ty = threadIdx.x >> 5;
        for (int r = ty; r < 32; r += 8)
            tile[r][tx] = se_w[(size_t)(rb_ + r)*256 + cb_ + tx];
        __syncthreads();
        for (int r = ty; r < 32; r += 8)
            se_wT[(size_t)(cb_ + r)*256 + rb_ + tx] = tile[tx][r];
    }
}

// ================= k_proj: S[16384][19] = (bq+bpos) @ W via MFMA; also znew + rp =================
// 256 blocks x 256 thr; block = 64 queries (wave = 16). Sg layout: [q][20], col 19 = znew.
__global__ __launch_bounds__(256) void k_proj(
    const float* __restrict__ bq, const float* __restrict__ bpos,
    const float* __restrict__ refp,
    const float* __restrict__ w_pos, const float* __restrict__ b_pos,
    const float* __restrict__ w_img, const float* __restrict__ w_att,
    float* __restrict__ Sg, float* __restrict__ out_rp)
{
    __shared__ float wlf[19][260];          // [j][c], +4 pad
    __shared__ unsigned short Aq[64][264];  // bf16 q rows, +8 pad
    __shared__ float sl[64][20];
    int tid = threadIdx.x;
    int lane = tid & 63, wid = tid >> 6;
    int l15 = lane & 15, quad = lane >> 4;
    int q0 = blockIdx.x * 64;

    // ---- stage W (f32, coalesced) ----
    wlf[0][tid] = w_pos[tid];
    #pragma unroll
    for (int r = 0; r < 6; r++){
        int idx = r*256 + tid;
        int c = idx / 6, j = idx - 6*c;
        wlf[1 + j][c] = w_att[idx];
    }
    #pragma unroll
    for (int r = 0; r < 12; r++){
        int idx = r*256 + tid;
        int c = idx / 12, j = idx - 12*c;
        wlf[7 + j][c] = w_img[idx];
    }
    // ---- stage Q = bq + bpos (bf16) ----
    #pragma unroll
    for (int r = 0; r < 16; r++){
        int row = r*4 + wid;
        int cc  = lane * 4;
        float4 a = *(const float4*)(bq   + (size_t)(q0+row)*CCH + cc);
        float4 b = *(const float4*)(bpos + (size_t)(q0+row)*CCH + cc);
        us4 o;
        o.x = f2bf(a.x+b.x); o.y = f2bf(a.y+b.y); o.z = f2bf(a.z+b.z); o.w = f2bf(a.w+b.w);
        *(us4*)&Aq[row][cc] = o;
    }
    __syncthreads();

    f4_t acc0 = (f4_t){0.f,0.f,0.f,0.f};
    f4_t acc1 = (f4_t){0.f,0.f,0.f,0.f};
    #pragma unroll
    for (int kc = 0; kc < 8; kc++){
        bf8_t af = *(bf8_t*)&Aq[wid*16 + l15][kc*32 + quad*8];
        bf8_t b0, b1;
        {
            const float* wr = &wlf[l15][kc*32 + quad*8];
            float4 w0 = *(const float4*)wr;
            float4 w1 = *(const float4*)(wr + 4);
            b0[0]=(short)f2bf(w0.x); b0[1]=(short)f2bf(w0.y); b0[2]=(short)f2bf(w0.z); b0[3]=(short)f2bf(w0.w);
            b0[4]=(short)f2bf(w1.x); b0[5]=(short)f2bf(w1.y); b0[6]=(short)f2bf(w1.z); b0[7]=(short)f2bf(w1.w);
        }
        if (l15 < 3){
            const float* wr = &wlf[16 + l15][kc*32 + quad*8];
            float4 w0 = *(const float4*)wr;
            float4 w1 = *(const float4*)(wr + 4);
            b1[0]=(short)f2bf(w0.x); b1[1]=(short)f2bf(w0.y); b1[2]=(short)f2bf(w0.z); b1[3]=(short)f2bf(w0.w);
            b1[4]=(short)f2bf(w1.x); b1[5]=(short)f2bf(w1.y); b1[6]=(short)f2bf(w1.z); b1[7]=(short)f2bf(w1.w);
        } else {
            b1 = (bf8_t){0,0,0,0,0,0,0,0};
        }
        acc0 = __builtin_amdgcn_mfma_f32_16x16x32_bf16(af, b0, acc0, 0, 0, 0);
        acc1 = __builtin_amdgcn_mfma_f32_16x16x32_bf16(af, b1, acc1, 0, 0, 0);
    }
    // D: col = lane&15 (j), row = quad*4+reg (query within wave's 16)
    #pragma unroll
    for (int r = 0; r < 4; r++){
        int qq = wid*16 + quad*4 + r;
        sl[qq][l15] = acc0[r];
        if (l15 < 3) sl[qq][16 + l15] = acc1[r];
    }
    __syncthreads();

    if (tid < 64){
        int q = q0 + tid;
        float pos_off = sl[tid][0] + b_pos[0];
        float rx = refp[q*3+0], ry = refp[q*3+1], rz = refp[q*3+2];
        float zc_ = fminf(fmaxf(rz, 0.f), 1.f);
        float inv = logf(fmaxf(zc_, EPSV) / fmaxf(1.f - zc_, EPSV));
        float znew = sigmoidf_(inv + pos_off);
        out_rp[q*3+0] = rx; out_rp[q*3+1] = ry; out_rp[q*3+2] = znew;
        sl[tid][19] = znew;
    }
    __syncthreads();

    for (int i = tid; i < 64*20; i += 256)
        Sg[(size_t)q0*20 + i] = ((const float*)sl)[i];
}

// ================= k_geomagg: per-camera geometry + feature aggregation =================
// 2048 blocks x 256 thr; block = 8 queries, wave = 2 queries. Projections come from Sg.
__global__ __launch_bounds__(256) void k_geomagg(
    const float* __restrict__ refp, const float* __restrict__ pcr,
    const float* __restrict__ l2i, const float* __restrict__ dpr,
    const float* __restrict__ b_img, const float* __restrict__ b_att,
    const float* __restrict__ Sg, const unsigned short* __restrict__ feat_tH,
    unsigned short* __restrict__ aggH)
{
    __shared__ float sgl[8][20];
    __shared__ int   so_l[192];
    __shared__ float sw_l[192];
    int q0 = blockIdx.x * 8;
    int tid = threadIdx.x;
    int wid = tid >> 6, lane = tid & 63;

    if (tid < 160) ((float*)sgl)[tid] = Sg[(size_t)q0*20 + tid];
    __syncthreads();

    // ---- per-camera geometry: both queries of the wave in parallel ----
    {
        int sub = lane >> 5;        // 0: even query, 1: odd query
        int n   = lane & 31;        // camera
        if (n < NCAM){
            int ql = wid*2 + sub;
            int q  = q0 + ql;
            float att  = sgl[ql][1+n] + b_att[n];
            float offx = (sgl[ql][7+2*n] + b_img[2*n])   / (float)WFD;
            float offy = (sgl[ql][8+2*n] + b_img[2*n+1]) / (float)HFD;
            float znew = sgl[ql][19];
            float rx = refp[q*3+0], ry = refp[q*3+1];
            float lo0=pcr[0], lo1=pcr[1], lo2=pcr[2];
            float hi0=pcr[3], hi1=pcr[4], hi2=pcr[5];
            float px = rx*(hi0-lo0)+lo0, py = ry*(hi1-lo1)+lo1, pz = znew*(hi2-lo2)+lo2;
            const float* M = l2i + n*16;
            float cx = M[0]*px + M[1]*py + M[2]*pz  + M[3];
            float cy = M[4]*px + M[5]*py + M[6]*pz  + M[7];
            float cz = M[8]*px + M[9]*py + M[10]*pz + M[11];
            bool m = cz > EPSV;
            float zdiv = fmaxf(cz, EPSV);
            float u = (cx/zdiv)/IMGW; u = (u - 0.5f)*2.f;
            float v = (cy/zdiv)/IMGH; v = (v - 0.5f)*2.f;
            m = m && (u > -1.f) && (u < 1.f) && (v > -1.f) && (v < 1.f);
            float rdn = (cz/(float)DDD - 0.5f)*2.f;
            m = m && (rdn > -1.f) && (rdn < 1.f);

            int base = ql*24 + n*4;
            float wq = 0.f, xs = 0.f, ys = 0.f;
            if (m){
                float u2 = u + offx, v2 = v + offy;
                xs = (u2 + 1.f)*0.5f*WFD - 0.5f;
                ys = (v2 + 1.f)*0.5f*HFD - 0.5f;
                float zs = (rdn + 1.f)*0.5f*DDD - 0.5f;
                float fx = floorf(xs), fy = floorf(ys), fz = floorf(zs);
                int x0=(int)fx, y0=(int)fy, z0=(int)fz;
                float wx = xs-fx, wy = ys-fy, wz = zs-fz;
                float dp = 0.f;
                const float* vol = dpr + (size_t)n*DDD*HFD*WFD;
                #pragma unroll
                for (int dz=0; dz<2; dz++)
                #pragma unroll
                for (int dy=0; dy<2; dy++)
                #pragma unroll
                for (int dx=0; dx<2; dx++){
                    int ix=x0+dx, iy=y0+dy, iz=z0+dz;
                    if (ix>=0 && ix<WFD && iy>=0 && iy<HFD && iz>=0 && iz<DDD){
                        float ww = (dx?wx:1.f-wx)*(dy?wy:1.f-wy)*(dz?wz:1.f-wz);
                        dp += ww * vol[(size_t)(iz*HFD+iy)*WFD + ix];
                    }
                }
                wq = sigmoidf_(att) * dp;
            }
            if (m && wq != 0.f){
                float fx = floorf(xs), fy = floorf(ys);
                int x0=(int)fx, y0=(int)fy;
                float wx = xs-fx, wy = ys-fy;
                float cwv[4] = {(1.f-wx)*(1.f-wy), wx*(1.f-wy), (1.f-wx)*wy, wx*wy};
                int xi[4] = {x0, x0+1, x0, x0+1};
                int yi[4] = {y0, y0, y0+1, y0+1};
                #pragma unroll
                for (int k=0;k<4;k++){
                    bool ok = (xi[k]>=0 && xi[k]<WFD && yi[k]>=0 && yi[k]<HFD);
                    so_l[base+k] = ok ? ((n*HFD + yi[k])*WFD + xi[k]) : 0;
                    sw_l[base+k] = ok ? wq*cwv[k] : 0.f;
                }
            } else {
                #pragma unroll
                for (int k=0;k<4;k++){ so_l[base+k] = 0; sw_l[base+k] = 0.f; }
            }
        }
    }
    __syncthreads();

    // ---- gather: lane halves cover the wave's two queries, 8 ch/lane, unconditional ----
    {
        int half = lane >> 5, li = lane & 31;
        int c8 = li * 8;
        int ql = wid*2 + half;
        float a[8] = {0.f,0.f,0.f,0.f,0.f,0.f,0.f,0.f};
        #pragma unroll
        for (int k=0;k<24;k++){
            float w = sw_l[ql*24+k];
            us8 v = *(const us8*)(feat_tH + (size_t)so_l[ql*24+k]*CCH + c8);
            #pragma unroll
            for (int j=0;j<8;j++) a[j] += w * bf2f((unsigned short)v[j]);
        }
        us8 o;
        #pragma unroll
        for (int j=0;j<8;j++) o[j] = f2bf(a[j]);
        *(us8*)(aggH + (size_t)(q0+ql)*CCH + c8) = o;
    }
}

// ================= k_conv2: 3x3 conv + BN + ReLU + SE-sum, kw-folded MFMA =================
// block 256 thr (4 waves), tile 128 px (full BEV row) x 128 co, wave tile 64x64
__global__ __launch_bounds__(256, 2) void k_conv2(const unsigned short* __restrict__ aggH,
    const unsigned short* __restrict__ wtH, const float* __restrict__ conv_b,
    const float* __restrict__ bn_g, const float* __restrict__ bn_b,
    const float* __restrict__ bn_m, const float* __restrict__ bn_v,
    float* __restrict__ xN, float* __restrict__ ssum)
{
    __shared__ unsigned short Al[130][72];       // rows: input px w = row-1
    __shared__ unsigned short Bl[3][128][72];    // [kw][co][ci]
    __shared__ float sacc[128];

    int h   = blockIdx.x;           // BEV row
    int co0 = blockIdx.y * 128;
    int tid  = threadIdx.x;
    int lane = tid & 63, wid = tid >> 6;
    int m_q = (wid & 1) * 64;
    int n_q = (wid >> 1) * 64;
    int l15 = lane & 15, quad = lane >> 4;

    f4_t acc[4][4];
    #pragma unroll
    for (int i=0;i<4;i++)
    #pragma unroll
    for (int j=0;j<4;j++) acc[i][j] = (f4_t){0.f,0.f,0.f,0.f};

    int arow = tid >> 1;            // input px w 0..127 -> Al row arow+1
    int aseg = (tid & 1) * 32;      // ci segment start (shorts), 4x us8

    if (tid < 16){
        int r = (tid >> 3) ? 129 : 0;
        int sg = (tid & 7) * 8;
        *(us8*)&Al[r][sg] = (us8){0,0,0,0,0,0,0,0};
    }
    if (tid < 128) sacc[tid] = 0.f;

    us8 ra[4], rb[3][4];
    const us8 z8 = (us8){0,0,0,0,0,0,0,0};

    #define LOADSTAGE(s) { \
        int kh_ = (s) >> 2; \
        int ph_ = h + kh_ - 1; \
        if (ph_ >= 0 && ph_ < BEVH){ \
            const unsigned short* ap_ = aggH + ((size_t)(ph_*BEVW + arow)*CCH + (((s) & 3) << 6) + aseg); \
            ra[0] = *(const us8*)ap_;        ra[1] = *(const us8*)(ap_ + 8); \
            ra[2] = *(const us8*)(ap_ + 16); ra[3] = *(const us8*)(ap_ + 24); \
        } else { ra[0]=z8; ra[1]=z8; ra[2]=z8; ra[3]=z8; } \
        const unsigned short* bp_ = wtH + (size_t)(s)*49152 + (size_t)co0*64; \
        _Pragma("unroll") \
        for (int kw_=0; kw_<3; kw_++){ \
            _Pragma("unroll") \
            for (int j_=0; j_<4; j_++) \
                rb[kw_][j_] = *(const us8*)(bp_ + kw_*16384 + (j_*256 + tid)*8); \
        } \
    }

    LOADSTAGE(0);
    for (int s=0; s<12; s++){
        __syncthreads();
        *(us8*)&Al[arow+1][aseg]      = ra[0];
        *(us8*)&Al[arow+1][aseg+8]    = ra[1];
        *(us8*)&Al[arow+1][aseg+16]   = ra[2];
        *(us8*)&Al[arow+1][aseg+24]   = ra[3];
        {
            int bco = tid >> 3;
            int ciin = (tid & 7) * 8;
            #pragma unroll
            for (int kw_=0; kw_<3; kw_++){
                #pragma unroll
                for (int j_=0; j_<4; j_++)
                    *(us8*)&Bl[kw_][j_*32 + bco][ciin] = rb[kw_][j_];
            }
        }
        __syncthreads();
        if (s < 11) LOADSTAGE(s+1);
        #pragma unroll
        for (int ks=0; ks<2; ks++){
            #pragma unroll
            for (int kw=0; kw<3; kw++){
                bf8_t af[4], bfr[4];
                #pragma unroll
                for (int i=0;i<4;i++) af[i]  = *(bf8_t*)&Al[m_q + i*16 + l15 + kw][ks*32 + quad*8];
                #pragma unroll
                for (int j=0;j<4;j++) bfr[j] = *(bf8_t*)&Bl[kw][n_q + j*16 + l15][ks*32 + quad*8];
                #pragma unroll
                for (int i=0;i<4;i++)
                #pragma unroll
                for (int j=0;j<4;j++)
                    acc[i][j] = __builtin_amdgcn_mfma_f32_16x16x32_bf16(af[i], bfr[j], acc[i][j], 0, 0, 0);
            }
        }
    }
    #undef LOADSTAGE

    #pragma unroll
    for (int j=0;j<4;j++){
        int col = n_q + j*16 + l15;
        int co = co0 + col;
        float sc = bn_g[co] * rsqrtf(bn_v[co] + 1e-5f);
        float sh = bn_b[co] - bn_m[co]*sc;
        float cb = conv_b[co];
        float part = 0.f;
        #pragma unroll
        for (int i=0;i<4;i++){
            #pragma unroll
            for (int r=0;r<4;r++){
                int m = m_q + i*16 + quad*4 + r;
                int p = h*BEVW + m;
                float y = fmaxf((acc[i][j][r] + cb)*sc + sh, 0.f);
                xN[(size_t)p*CCH + co] = y;
                part += y;
            }
        }
        atomicAdd(&sacc[col], part);
    }
    __syncthreads();
    if (tid < 128) atomicAdd(&ssum[co0 + tid], sacc[tid]);
}

// ================= k_maps2: SE scale (coalesced via se_wT) + CBAM channel maps =================
__global__ __launch_bounds__(256) void k_maps2(const float* __restrict__ xN,
    const float* __restrict__ ssum, const float* __restrict__ se_wT, const float* __restrict__ se_b,
    float* __restrict__ scale_g, float* __restrict__ amax, float* __restrict__ amean)
{
    __shared__ float smv[256];
    __shared__ float scl[256];
    int t = threadIdx.x;
    smv[t] = ssum[t] * (1.f/16384.f);
    __syncthreads();
    float a0=0.f, a1=0.f, a2=0.f, a3=0.f;
    for (int k=0; k<256; k+=4){
        a0 += smv[k]   * se_wT[(size_t)(k  )*256 + t];
        a1 += smv[k+1] * se_wT[(size_t)(k+1)*256 + t];
        a2 += smv[k+2] * se_wT[(size_t)(k+2)*256 + t];
        a3 += smv[k+3] * se_wT[(size_t)(k+3)*256 + t];
    }
    float sv = sigmoidf_(se_b[t] + ((a0+a1)+(a2+a3)));
    scl[t] = sv;
    if (blockIdx.x == 0) scale_g[t] = sv;
    __syncthreads();

    int wid = t >> 6, lane = t & 63;
    int p0 = blockIdx.x * 64;
    float4 sc = *(const float4*)&scl[lane*4];
    for (int i=0; i<16; i++){
        int p = p0 + i*4 + wid;
        float4 v = *(const float4*)&xN[(size_t)p*CCH + lane*4];
        float a = v.x*sc.x, b = v.y*sc.y, c = v.z*sc.z, d = v.w*sc.w;
        float mx = fmaxf(fmaxf(a,b), fmaxf(c,d));
        float sm = a+b+c+d;
        #pragma unroll
        for (int off=1; off<64; off<<=1){
            mx = fmaxf(mx, __shfl_xor(mx, off, 64));
            sm += __shfl_xor(sm, off, 64);
        }
        if (lane == 0){ amax[p] = mx; amean[p] = sm*(1.f/256.f); }
    }
}

// ================= k_final2: CBAM 7x7 (in-block) + final scaling =================
__global__ __launch_bounds__(256) void k_final2(const float* __restrict__ xN,
    const float* __restrict__ scale_g, const float* __restrict__ amax, const float* __restrict__ amean,
    const float* __restrict__ cw, const float* __restrict__ cb, float* __restrict__ out)
{
    __shared__ float am2[7][128];
    __shared__ float av2[7][128];
    __shared__ float wcb[98];
    __shared__ float scl[256];
    __shared__ float amap_l[64];

    int b = blockIdx.x;
    int h  = b >> 1;
    int w0 = (b & 1) * 64;
    int t = threadIdx.x;

    scl[t] = scale_g[t];
    if (t < 98) wcb[t] = cw[t];
    for (int idx = t; idx < 896; idx += 256){
        int r = idx >> 7, c = idx & 127;
        int ph = h + r - 3;
        bool ok = (ph >= 0 && ph < BEVH);
        am2[r][c] = ok ? amax[ph*BEVW + c] : 0.f;
        av2[r][c] = ok ? amean[ph*BEVW + c] : 0.f;
    }
    __syncthreads();

    if (t < 64){
        int px = w0 + t;
        float acc = cb[0];
        #pragma unroll
        for (int kh=0; kh<7; kh++){
            #pragma unroll
            for (int kw=0; kw<7; kw++){
                int pw = px + kw - 3;
                if (pw >= 0 && pw < BEVW)
                    acc += am2[kh][pw]*wcb[kh*7+kw] + av2[kh][pw]*wcb[49 + kh*7+kw];
            }
        }
        amap_l[t] = sigmoidf_(acc);
    }
    __syncthreads();

    int lane = t & 63, sub = t >> 6;
    int c4 = lane * 4;
    float4 sc = *(const float4*)&scl[c4];
    for (int i=0; i<16; i++){
        int pxl = sub*16 + i;
        int p = h*BEVW + w0 + pxl;
        float am = amap_l[pxl];
        float4 v = *(const float4*)&xN[(size_t)p*CCH + c4];
        float4 o;
        o.x = v.x*sc.x*am; o.y = v.y*sc.y*am; o.z = v.z*sc.z*am; o.w = v.w*sc.w*am;
        *(float4*)&out[(size_t)p*CCH + c4] = o;
    }
}

extern "C" void kernel_launch(void* const* d_in, const int* in_sizes, int n_in,
                              void* d_out, int out_size, void* d_ws, size_t ws_size,
                              hipStream_t stream) {
    const float* feat   = (const float*)d_in[0];
    const float* bq     = (const float*)d_in[1];
    const float* bpos   = (const float*)d_in[2];
    const float* refp   = (const float*)d_in[3];
    const float* pcr    = (const float*)d_in[4];
    const float* l2i    = (const float*)d_in[5];
    const float* dpr    = (const float*)d_in[6];
    const float* w_pos  = (const float*)d_in[7];
    const float* b_pos  = (const float*)d_in[8];
    const float* w_img  = (const float*)d_in[9];
    const float* b_img  = (const float*)d_in[10];
    const float* w_att  = (const float*)d_in[11];
    const float* b_att  = (const float*)d_in[12];
    const float* conv_w = (const float*)d_in[13];
    const float* conv_b = (const float*)d_in[14];
    const float* bn_g   = (const float*)d_in[15];
    const float* bn_b   = (const float*)d_in[16];
    const float* bn_m   = (const float*)d_in[17];
    const float* bn_v   = (const float*)d_in[18];
    const float* se_w   = (const float*)d_in[19];
    const float* se_b   = (const float*)d_in[20];
    const float* cbw    = (const float*)d_in[21];
    const float* cbb    = (const float*)d_in[22];
    float* out = (float*)d_out;

    float* ws = (float*)d_ws;
    size_t o = 0;
    unsigned short* feat_tH = (unsigned short*)(ws + o); o += (size_t)6*2816*128;  // bf16
    unsigned short* wtH  = (unsigned short*)(ws + o); o += (size_t)9*256*128;      // bf16
    unsigned short* aggH = (unsigned short*)(ws + o); o += (size_t)QN*128;         // bf16
    float* xN      = ws + o;  o += (size_t)QN*256;
    float* se_wT   = ws + o;  o += (size_t)256*256;
    float* Sg      = ws + o;  o += (size_t)QN*20;
    float* ssum    = ws + o;  o += 256;
    float* scale_g = ws + o;  o += 256;
    float* amax    = ws + o;  o += QN;
    float* amean   = ws + o;  o += QN;

    k_prep<<<6592, 256, 0, stream>>>(feat, feat_tH, conv_w, wtH, se_w, se_wT, ssum);
    k_proj<<<256, 256, 0, stream>>>(bq, bpos, refp, w_pos, b_pos, w_img, w_att,
                                    Sg, out + (size_t)QN*256);
    k_geomagg<<<2048, 256, 0, stream>>>(refp, pcr, l2i, dpr, b_img, b_att,
                                        Sg, feat_tH, aggH);
    k_conv2<<<dim3(128,2), 256, 0, stream>>>(aggH, wtH, conv_b, bn_g, bn_b, bn_m, bn_v, xN, ssum);
    k_maps2<<<256, 256, 0, stream>>>(xN, ssum, se_wT, se_b, scale_g, amax, amean);
    k_final2<<<256, 256, 0, stream>>>(xN, scale_g, amax, amean, cbw, cbb, out);
}